// Round 1
// baseline (4322.271 us; speedup 1.0000x reference)
//
#include <hip/hip_runtime.h>

// ConvTranspose2d(64->64, k=3, s=1, p=0), fp32.
// x: (2, 64, 1024, 1024), w: (64, 64, 3, 3) [in, out, kh, kw], out: (2, 64, 1026, 1026)
// out[n,co,oy,ox] = sum_{ci,kh,kw} w[ci,co,kh,kw] * x[n,ci,oy-kh,ox-kw]  (valid x range)

#define C_IN   64
#define C_OUT  64
#define H      1024
#define W      1024
#define OH     1026
#define OW     1026
#define TW     64
#define TH     4
#define SROWS  (TH + 2)   // 6
#define SCOLS  (TW + 2)   // 66

__global__ __launch_bounds__(256, 2)
void convt3x3_fp32_kernel(const float* __restrict__ x,
                          const float* __restrict__ w,
                          float* __restrict__ out) {
    __shared__ float s[SROWS][SCOLS];

    const int tx = threadIdx.x;          // 0..63
    const int ty = threadIdx.y;          // 0..3
    const int n  = blockIdx.z;

    const int ox0 = blockIdx.x * TW;
    const int oy0 = blockIdx.y * TH;
    const int base_x = ox0 - 2;
    const int base_y = oy0 - 2;

    const int oy = oy0 + ty;
    const int ox = ox0 + tx;
    const int lin = ty * TW + tx;        // 0..255

    float acc[C_OUT];
#pragma unroll
    for (int co = 0; co < C_OUT; ++co) acc[co] = 0.0f;

    for (int ci = 0; ci < C_IN; ++ci) {
        __syncthreads();   // previous iteration's LDS reads done before overwrite

        // ---- stage 6x66 halo tile (zero-padded at image borders) ----
        const float* xp = x + ((n * C_IN + ci) * H) * (long)W;
#pragma unroll
        for (int k = 0; k < 2; ++k) {
            int idx = lin + k * 256;
            if (idx < SROWS * SCOLS) {
                int r = idx / SCOLS;
                int c = idx - r * SCOLS;
                int gy = base_y + r;
                int gx = base_x + c;
                float v = 0.0f;
                if ((unsigned)gy < (unsigned)H && (unsigned)gx < (unsigned)W)
                    v = xp[gy * W + gx];
                s[r][c] = v;
            }
        }
        __syncthreads();

        // ---- load 3x3 patch for this output pixel ----
        float p[3][3];
#pragma unroll
        for (int kh = 0; kh < 3; ++kh)
#pragma unroll
            for (int kw = 0; kw < 3; ++kw)
                p[kh][kw] = s[ty + 2 - kh][tx + 2 - kw];

        // ---- 64 output channels x 9 taps; weight index is wave-uniform ----
        const float* wp = w + ci * (C_OUT * 9);
#pragma unroll
        for (int co = 0; co < C_OUT; ++co) {
#pragma unroll
            for (int kh = 0; kh < 3; ++kh)
#pragma unroll
                for (int kw = 0; kw < 3; ++kw)
                    acc[co] = fmaf(wp[co * 9 + kh * 3 + kw], p[kh][kw], acc[co]);
        }
    }

    if (oy < OH && ox < OW) {
#pragma unroll
        for (int co = 0; co < C_OUT; ++co)
            out[((n * C_OUT + co) * OH + oy) * (long)OW + ox] = acc[co];
    }
}

extern "C" void kernel_launch(void* const* d_in, const int* in_sizes, int n_in,
                              void* d_out, int out_size, void* d_ws, size_t ws_size,
                              hipStream_t stream) {
    const float* x = (const float*)d_in[0];
    const float* w = (const float*)d_in[1];
    float* out = (float*)d_out;

    dim3 block(TW, TH, 1);                               // 256 threads
    dim3 grid((OW + TW - 1) / TW,                        // 17
              (OH + TH - 1) / TH,                        // 257
              2);                                        // batch
    convt3x3_fp32_kernel<<<grid, block, 0, stream>>>(x, w, out);
}

// Round 5
// 1619.305 us; speedup vs baseline: 2.6692x; 2.6692x over previous
//
#include <hip/hip_runtime.h>
#include <stdint.h>
#include <stddef.h>

// ConvTranspose2d(64->64, k=3, s=1, p=0) as split-bf16 MFMA GEMM.
// out[n,co,oy,ox] = sum_{ci,kh,kw} w[ci,co,kh,kw] * x[n,ci,oy-kh,ox-kw]
// x fp32 -> (xhi + xlo) bf16, w fp32 -> (whi + wlo) bf16;
// out ~= xhi*whi + xlo*whi + xhi*wlo   (drop xlo*wlo, ~2^-18 relative)

#define CI 64
#define CO 64
#define H  1024
#define W  1024
#define OH 1026
#define OW 1026

typedef __attribute__((ext_vector_type(8)))  short short8;
typedef __attribute__((ext_vector_type(16))) float f32x16;

__device__ __forceinline__ uint16_t f32_to_bf16_rne(float f) {
    uint32_t u = __builtin_bit_cast(uint32_t, f);
    uint32_t r = (u + 0x7FFFu + ((u >> 16) & 1u)) >> 16;
    return (uint16_t)r;
}
__device__ __forceinline__ float bf16_to_f32(uint16_t h) {
    uint32_t u = ((uint32_t)h) << 16;
    return __builtin_bit_cast(float, u);
}

// ---- pre-kernel: split w (CI,CO,3,3) fp32 into whi/wlo bf16, layout [tap][co][ci]
__global__ void wsplit_kernel(const float* __restrict__ w,
                              uint16_t* __restrict__ whi,
                              uint16_t* __restrict__ wlo) {
    int idx = blockIdx.x * 256 + threadIdx.x;          // idx = (ci*CO + co)*9 + tap
    if (idx >= CI * CO * 9) return;
    int tap = idx % 9;
    int co  = (idx / 9) % CO;
    int ci  = idx / (9 * CO);
    float v = w[idx];
    uint16_t hi = f32_to_bf16_rne(v);
    uint16_t lo = f32_to_bf16_rne(v - bf16_to_f32(hi));
    int o = (tap * CO + co) * CI + ci;
    whi[o] = hi;
    wlo[o] = lo;
}

// ---- main kernel: block = 4 waves; each wave computes 64co x 64pix (one output row)
// LDS: x halo tile 6 rows x 66 cols x 32 ci (per kc chunk), bf16 hi+lo,
// layout [row][col][ci-pair q] with swizzle q = p ^ (((c>>1)&3)<<2).
// Read side: the 4 pairs p = (ks*2+g)*4 + {0..3} are contiguous at
// q = ((ks*2+g)^((c>>1)&3))*4 + {0..3}  -> one ds_read_b128, conflict-free
// (8 consecutive lanes cover all 32 banks exactly once).
__global__ __launch_bounds__(256, 2)
void convt_mfma(const float* __restrict__ x,
                const uint16_t* __restrict__ whi,
                const uint16_t* __restrict__ wlo,
                float* __restrict__ out) {
    __shared__ uint16_t xhi[6 * 66 * 32];
    __shared__ uint16_t xlo[6 * 66 * 32];

    const int tid  = threadIdx.x;
    const int w_id = tid >> 6;       // wave 0..3 -> output row in tile
    const int lane = tid & 63;
    const int l31  = lane & 31;      // col-in-group / co-in-block
    const int g    = lane >> 5;      // lane group (k-slot high bits)

    const int n   = blockIdx.z;
    const int oy0 = blockIdx.y * 4;
    const int ox0 = blockIdx.x * 64;

    f32x16 acc00 = {0.f}, acc01 = {0.f}, acc10 = {0.f}, acc11 = {0.f};

    const float* xbase = x + (size_t)n * CI * H * W;

    for (int kc = 0; kc < 2; ++kc) {
        __syncthreads();             // previous chunk's LDS reads complete

        // ---- stage 32 ci-planes of the 6x66 halo as bf16 hi/lo ----
        // idx = p*396 + row*66 + c ; p = ci-pair 0..15
        for (int it = 0; it < 25; ++it) {
            int idx = tid + it * 256;
            if (idx < 6336) {
                int p   = idx / 396;
                int rr  = idx - p * 396;
                int row = rr / 66;
                int c   = rr - row * 66;
                int gy  = oy0 - 2 + row;
                int gx  = ox0 - 2 + c;
                int ci  = kc * 32 + p * 2;
                float v0 = 0.f, v1 = 0.f;
                if ((unsigned)gy < (unsigned)H && (unsigned)gx < (unsigned)W) {
                    const float* pp = xbase + ((size_t)ci * H + gy) * W + gx;
                    v0 = pp[0];
                    v1 = pp[(size_t)H * W];
                }
                uint16_t h0 = f32_to_bf16_rne(v0);
                uint16_t h1 = f32_to_bf16_rne(v1);
                uint16_t e0 = f32_to_bf16_rne(v0 - bf16_to_f32(h0));
                uint16_t e1 = f32_to_bf16_rne(v1 - bf16_to_f32(h1));
                int q    = p ^ (((c >> 1) & 3) << 2);          // swizzled pair slot
                int slot = (row * 66 + c) * 16 + q;            // u32 units
                ((uint32_t*)xhi)[slot] = (uint32_t)h0 | ((uint32_t)h1 << 16);
                ((uint32_t*)xlo)[slot] = (uint32_t)e0 | ((uint32_t)e1 << 16);
            }
        }
        __syncthreads();

        // ---- compute: 9 taps x 2 k-steps, 3 split products ----
#pragma unroll
        for (int kh = 0; kh < 3; ++kh) {
            const int row6 = w_id + 2 - kh;                    // 0..5
#pragma unroll
            for (int kw = 0; kw < 3; ++kw) {
                const int tap = kh * 3 + kw;
                // A fragments (weights) straight from L2-resident ws buffers.
                // semantic ci = kc*32 + ks*16 + g*8 + i  (same bijection as B)
                short8 ah0[2], ah1[2], al0[2], al1[2];
#pragma unroll
                for (int ks = 0; ks < 2; ++ks) {
                    int wi0 = (tap * CO +      l31) * CI + kc * 32 + ks * 16 + g * 8;
                    int wi1 = (tap * CO + 32 + l31) * CI + kc * 32 + ks * 16 + g * 8;
                    ah0[ks] = *(const short8*)(whi + wi0);
                    ah1[ks] = *(const short8*)(whi + wi1);
                    al0[ks] = *(const short8*)(wlo + wi0);
                    al1[ks] = *(const short8*)(wlo + wi1);
                }
#pragma unroll
                for (int ng = 0; ng < 2; ++ng) {
                    int c    = ng * 32 + l31 + 2 - kw;         // 0..65
                    int base = (row6 * 66 + c) * 32;           // uint16 units
                    int sw2  = (c >> 1) & 3;
#pragma unroll
                    for (int ks = 0; ks < 2; ++ks) {
                        int run = (ks * 2 + g) ^ sw2;          // un-swizzle
                        const short8 bh = *(const short8*)(xhi + base + run * 8);
                        const short8 bl = *(const short8*)(xlo + base + run * 8);
                        if (ng == 0) {
                            acc00 = __builtin_amdgcn_mfma_f32_32x32x16_bf16(ah0[ks], bh, acc00, 0, 0, 0);
                            acc10 = __builtin_amdgcn_mfma_f32_32x32x16_bf16(ah1[ks], bh, acc10, 0, 0, 0);
                            acc00 = __builtin_amdgcn_mfma_f32_32x32x16_bf16(al0[ks], bh, acc00, 0, 0, 0);
                            acc10 = __builtin_amdgcn_mfma_f32_32x32x16_bf16(al1[ks], bh, acc10, 0, 0, 0);
                            acc00 = __builtin_amdgcn_mfma_f32_32x32x16_bf16(ah0[ks], bl, acc00, 0, 0, 0);
                            acc10 = __builtin_amdgcn_mfma_f32_32x32x16_bf16(ah1[ks], bl, acc10, 0, 0, 0);
                        } else {
                            acc01 = __builtin_amdgcn_mfma_f32_32x32x16_bf16(ah0[ks], bh, acc01, 0, 0, 0);
                            acc11 = __builtin_amdgcn_mfma_f32_32x32x16_bf16(ah1[ks], bh, acc11, 0, 0, 0);
                            acc01 = __builtin_amdgcn_mfma_f32_32x32x16_bf16(al0[ks], bh, acc01, 0, 0, 0);
                            acc11 = __builtin_amdgcn_mfma_f32_32x32x16_bf16(al1[ks], bh, acc11, 0, 0, 0);
                            acc01 = __builtin_amdgcn_mfma_f32_32x32x16_bf16(ah0[ks], bl, acc01, 0, 0, 0);
                            acc11 = __builtin_amdgcn_mfma_f32_32x32x16_bf16(ah1[ks], bl, acc11, 0, 0, 0);
                        }
                    }
                }
            }
        }
    }

    // ---- epilogue: C/D layout col=lane&31, row=(reg&3)+8*(reg>>2)+4*(lane>>5) ----
    const int oy = oy0 + w_id;
    if (oy < OH) {
#pragma unroll
        for (int mb = 0; mb < 2; ++mb) {
#pragma unroll
            for (int ng = 0; ng < 2; ++ng) {
                const f32x16 a = (mb == 0) ? (ng == 0 ? acc00 : acc01)
                                           : (ng == 0 ? acc10 : acc11);
                int ox = ox0 + ng * 32 + l31;
                if (ox < OW) {
#pragma unroll
                    for (int reg = 0; reg < 16; ++reg) {
                        int co = mb * 32 + (reg & 3) + 8 * (reg >> 2) + 4 * g;
                        out[(((size_t)n * CO + co) * OH + oy) * OW + ox] = a[reg];
                    }
                }
            }
        }
    }
}

extern "C" void kernel_launch(void* const* d_in, const int* in_sizes, int n_in,
                              void* d_out, int out_size, void* d_ws, size_t ws_size,
                              hipStream_t stream) {
    const float* x = (const float*)d_in[0];
    const float* w = (const float*)d_in[1];
    float* out = (float*)d_out;

    uint16_t* whi = (uint16_t*)d_ws;            // 36864 bf16 = 73728 B
    uint16_t* wlo = whi + CI * CO * 9;          // another 73728 B

    wsplit_kernel<<<(CI * CO * 9 + 255) / 256, 256, 0, stream>>>(w, whi, wlo);

    dim3 block(256, 1, 1);
    dim3 grid((OW + 63) / 64,                   // 17
              (OH + 3) / 4,                     // 257
              2);                               // batch
    convt_mfma<<<grid, block, 0, stream>>>(x, whi, wlo, out);
}